// Round 2
// baseline (124.965 us; speedup 1.0000x reference)
//
#include <hip/hip_runtime.h>
#include <hip/hip_cooperative_groups.h>

namespace cg = cooperative_groups;

// HistogramLoss: total = emd(hist(rgb_in),hist(rgb_ref)) + emd(hist(yuv_in),hist(yuv_ref))
// emd collapses to sum_k (64-k)*(h1_k - h2_k); bins tile [-0.05,1.05] disjointly.
//
// R4 (66.2us, absmax 0.0): all-f32 bin-coordinate formulation; removed all f64
// VALU and the LDS centers table. Profile is now wall-to-wall harness poison
// fills (268MB d_ws fill ~41us @80% HBM, uncontrollable) -- our two kernels
// are worth ~5-7us of execution; the rest of the gap to the ~47-50us floor is
// dispatch count / inter-dispatch gaps.
//
// R5: merge the two kernels into ONE cooperative launch (grid.sync between
// per-block partials and the block-0 final reduce). Saves one dispatch + its
// graph gap. Phase-1 math is byte-identical to R4 (absmax 0.0 preserved).
// Residency: 1024 blocks x 256 thr, ~40 VGPR -> 8 blocks/CU x 256 CU = 2048
// capacity >= 1024, cooperative launch fits with margin.

#define HW    65536             // 256*256
#define NPIX  524288            // 8 * HW pixel positions
#define BLOCK 256
#define PXT   2                 // pixels per thread (adjacent -> float2 loads)
#define NBLK  (NPIX / (BLOCK * PXT))   // 1024

__device__ __forceinline__ void contrib(float v, float ivs, float go, float Ls,
                                        float& aW, float& aE) {
  float u  = (v + 1.0f) * 0.5f;     // matches reference rounding (add then mul)
  float g  = fmaf(u, ivs, go);      // (u+0.05)/step - 0.5
  float kf = floorf(g);
  float f  = g - kf;                // in [0,1), exact (|g| < 2^23)
  // candidate k0=kf: in-window iff f<0.5, weight 64-kf
  // candidate k0+1 : in-window iff f>0.5, weight 63-kf
  // at most one passes (disjoint tiling); f==0.5 -> neither (matches t>0 strict)
  float t0 = 0.5f - f;
  float t1 = f - 0.5f;
  bool in0 = (t0 > 0.0f) && (fabsf(kf - 31.5f) < 32.5f);  // kf in [0,63]
  bool in1 = (t1 > 0.0f) && (fabsf(kf - 30.5f) < 32.5f);  // kf in [-1,62]
  float w0 = in0 ? (64.0f - kf) : 0.0f;
  float w1 = in1 ? (63.0f - kf) : 0.0f;
  float z0 = t0 * Ls;               // z = ln(1.01f) * t,  t = step * t'
  float z1 = t1 * Ls;
  float e0 = fmaf(0.5f * z0, z0, z0);   // expm1(z), O(z^3) ~ 1e-13 dropped
  float e1 = fmaf(0.5f * z1, z1, z1);
  aW += w0 + w1;                    // exact integer part (f32-exact)
  aE  = fmaf(w0, e0, aE);
  aE  = fmaf(w1, e1, aE);
}

__global__ __launch_bounds__(BLOCK) void hl_fused(
    const float* __restrict__ img_in, const float* __restrict__ img_ref,
    double* __restrict__ partials, float* __restrict__ out) {
  __shared__ double redW[4], redE[4];

  // Replicate np.linspace(-0.05, 1.05, 65) step in f64, then cast constants.
  const double step = (1.05 - (-0.05)) / 64.0;
  const float  ivs = (float)(1.0 / step);            // 1/step
  const float  go  = (float)(0.05 / step - 0.5);     // (u+0.05)/step - 0.5 offset
  const float  Ls  = (float)(log((double)1.01f) * step);  // ln(f32(1.01)) * step

  // f32 YUV coefficients; f32 fma dot (reference einsum is f32)
  const float Y0 = 0.299f,    Y1 = 0.587f,    Y2 = 0.114f;
  const float U0 = -0.14713f, U1 = -0.28886f, U2 = 0.436f;
  const float V0 = 0.615f,    V1 = -0.51499f, V2 = -0.10001f;

  float aWp = 0.f, aWn = 0.f;   // + image / - image integer parts (f32-exact)
  float aEp = 0.f, aEn = 0.f;   // soft parts

  const int pair = blockIdx.x * BLOCK + threadIdx.x;   // 2 adjacent pixels
  const int p    = pair << 1;
  const int b    = p >> 16;              // batch (uniform per block: 512 | HW)
  const int hw   = p & (HW - 1);
  const float2* pi = (const float2*)(img_in  + (size_t)b * (3 * HW) + hw);
  const float2* pr = (const float2*)(img_ref + (size_t)b * (3 * HW) + hw);
  float2 r0 = pi[0], g0 = pi[HW / 2], b0 = pi[HW];     // strides in float2 units
  float2 r1 = pr[0], g1 = pr[HW / 2], b1 = pr[HW];

  const float rr0[2] = { r0.x, r0.y }, gg0[2] = { g0.x, g0.y }, bb0[2] = { b0.x, b0.y };
  const float rr1[2] = { r1.x, r1.y }, gg1[2] = { g1.x, g1.y }, bb1[2] = { b1.x, b1.y };

  #pragma unroll
  for (int i = 0; i < PXT; ++i) {
    float ri = rr0[i], gi = gg0[i], bi = bb0[i];
    float rj = rr1[i], gj = gg1[i], bj = bb1[i];

    // RGB
    contrib(ri, ivs, go, Ls, aWp, aEp);
    contrib(gi, ivs, go, Ls, aWp, aEp);
    contrib(bi, ivs, go, Ls, aWp, aEp);
    contrib(rj, ivs, go, Ls, aWn, aEn);
    contrib(gj, ivs, go, Ls, aWn, aEn);
    contrib(bj, ivs, go, Ls, aWn, aEn);

    // YUV in f32 (j-ascending fma chain like the einsum)
    float yi = fmaf(Y2, bi, fmaf(Y1, gi, Y0 * ri));
    float ui = fmaf(U2, bi, fmaf(U1, gi, U0 * ri));
    float vi = fmaf(V2, bi, fmaf(V1, gi, V0 * ri));
    float yj = fmaf(Y2, bj, fmaf(Y1, gj, Y0 * rj));
    float uj = fmaf(U2, bj, fmaf(U1, gj, U0 * rj));
    float vj = fmaf(V2, bj, fmaf(V1, gj, V0 * rj));

    contrib(yi, ivs, go, Ls, aWp, aEp);
    contrib(ui, ivs, go, Ls, aWp, aEp);
    contrib(vi, ivs, go, Ls, aWp, aEp);
    contrib(yj, ivs, go, Ls, aWn, aEn);
    contrib(uj, ivs, go, Ls, aWn, aEn);
    contrib(vj, ivs, go, Ls, aWn, aEn);
  }

  float  aW = aWp - aWn;                      // exact (integer-valued f32)
  double aE = (double)aEp - (double)aEn;

  // wave(64) shuffle reduction, then cross-wave via LDS
  #pragma unroll
  for (int off = 32; off > 0; off >>= 1) {
    aW += __shfl_down(aW, off);               // wave sum <= 98304: f32-exact
    aE += __shfl_down(aE, off);
  }
  int wv = threadIdx.x >> 6;
  if ((threadIdx.x & 63) == 0) { redW[wv] = (double)aW; redE[wv] = aE; }
  __syncthreads();

  if (threadIdx.x == 0) {
    double sW = 0.0, sE = 0.0;
    #pragma unroll
    for (int w = 0; w < 4; ++w) { sW += redW[w]; sE += redE[w]; }
    partials[2 * blockIdx.x]     = sW;
    partials[2 * blockIdx.x + 1] = sE;
  }

  // ---- grid-wide sync, then block 0 does the final reduce (was hl_final) ----
  cg::this_grid().sync();

  if (blockIdx.x == 0) {
    double sW = 0.0, sE = 0.0;
    for (int bb = threadIdx.x; bb < NBLK; bb += BLOCK) {
      sW += partials[2 * bb];
      sE += partials[2 * bb + 1];
    }
    #pragma unroll
    for (int off = 32; off > 0; off >>= 1) {
      sW += __shfl_down(sW, off);
      sE += __shfl_down(sE, off);
    }
    __syncthreads();   // redW/redE reuse after phase-1 writes
    int wv2 = threadIdx.x >> 6;
    if ((threadIdx.x & 63) == 0) { redW[wv2] = sW; redE[wv2] = sE; }
    __syncthreads();
    if (threadIdx.x == 0) {
      double tW = 0.0, tE = 0.0;
      #pragma unroll
      for (int w = 0; w < 4; ++w) { tW += redW[w]; tE += redE[w]; }
      out[0] = (float)((tW + tE) * (1.0 / (double)NPIX));
    }
  }
}

extern "C" void kernel_launch(void* const* d_in, const int* in_sizes, int n_in,
                              void* d_out, int out_size, void* d_ws, size_t ws_size,
                              hipStream_t stream) {
  const float* img_in  = (const float*)d_in[0];
  const float* img_ref = (const float*)d_in[1];
  float* out = (float*)d_out;
  double* partials = (double*)d_ws;   // 2*NBLK doubles = 16 KB

  void* args[] = { (void*)&img_in, (void*)&img_ref, (void*)&partials, (void*)&out };
  hipLaunchCooperativeKernel((const void*)hl_fused, dim3(NBLK), dim3(BLOCK),
                             args, 0, stream);
}

// Round 3
// 82.168 us; speedup vs baseline: 1.5209x; 1.5209x over previous
//
#include <hip/hip_runtime.h>

// HistogramLoss: total = emd(hist(rgb_in),hist(rgb_ref)) + emd(hist(yuv_in),hist(yuv_ref))
// emd collapses to sum_k (64-k)*(h1_k - h2_k); bins tile [-0.05,1.05] disjointly.
//
// R4 (66.2us, absmax 0.0): all-f32 bin-coordinate formulation, two dispatches.
// R5 (125us): cooperative grid.sync cost ~45us in-kernel (1024-block barrier
//   across 8 non-coherent XCDs) -- grid barrier is ~10x the dispatch it saved.
// R6: single dispatch WITHOUT a grid barrier: publish/spin last-reducer.
//   Each block relaxed-atomic-stores its (W,E) partial, then release-stores
//   two magic tags M1^i, M2^i (agent scope). Only block 0 spins (acquire
//   loads) until all 1024 slots show BOTH tags, then reduces exactly like
//   R4's hl_final (same summation order -> same bits). Publishers never
//   wait -> no deadlock regardless of scheduling. Two distinct-magic tags
//   defeat the unknown uniform workspace poison: poison P can equal M1^i for
//   at most one i and M2^j for at most one j, and i==j would force M1==M2.
//   Phase-1 math is byte-identical to R4 (absmax 0.0 preserved).

#define HW    65536             // 256*256
#define NPIX  524288            // 8 * HW pixel positions
#define BLOCK 256
#define PXT   2                 // pixels per thread (adjacent -> float2 loads)
#define NBLK  (NPIX / (BLOCK * PXT))   // 1024
#define MAG1  0x9E3779B9u
#define MAG2  0x85EBCA6Bu

__device__ __forceinline__ void contrib(float v, float ivs, float go, float Ls,
                                        float& aW, float& aE) {
  float u  = (v + 1.0f) * 0.5f;     // matches reference rounding (add then mul)
  float g  = fmaf(u, ivs, go);      // (u+0.05)/step - 0.5
  float kf = floorf(g);
  float f  = g - kf;                // in [0,1), exact (|g| < 2^23)
  // candidate k0=kf: in-window iff f<0.5, weight 64-kf
  // candidate k0+1 : in-window iff f>0.5, weight 63-kf
  // at most one passes (disjoint tiling); f==0.5 -> neither (matches t>0 strict)
  float t0 = 0.5f - f;
  float t1 = f - 0.5f;
  bool in0 = (t0 > 0.0f) && (fabsf(kf - 31.5f) < 32.5f);  // kf in [0,63]
  bool in1 = (t1 > 0.0f) && (fabsf(kf - 30.5f) < 32.5f);  // kf in [-1,62]
  float w0 = in0 ? (64.0f - kf) : 0.0f;
  float w1 = in1 ? (63.0f - kf) : 0.0f;
  float z0 = t0 * Ls;               // z = ln(1.01f) * t,  t = step * t'
  float z1 = t1 * Ls;
  float e0 = fmaf(0.5f * z0, z0, z0);   // expm1(z), O(z^3) ~ 1e-13 dropped
  float e1 = fmaf(0.5f * z1, z1, z1);
  aW += w0 + w1;                    // exact integer part (f32-exact)
  aE  = fmaf(w0, e0, aE);
  aE  = fmaf(w1, e1, aE);
}

__global__ __launch_bounds__(BLOCK) void hl_onepass(
    const float* __restrict__ img_in, const float* __restrict__ img_ref,
    double* __restrict__ pW, double* __restrict__ pE,
    unsigned* __restrict__ tagA, unsigned* __restrict__ tagB,
    float* __restrict__ out) {
  __shared__ double redW[4], redE[4];

  // Replicate np.linspace(-0.05, 1.05, 65) step in f64, then cast constants.
  const double step = (1.05 - (-0.05)) / 64.0;
  const float  ivs = (float)(1.0 / step);            // 1/step
  const float  go  = (float)(0.05 / step - 0.5);     // (u+0.05)/step - 0.5 offset
  const float  Ls  = (float)(log((double)1.01f) * step);  // ln(f32(1.01)) * step

  // f32 YUV coefficients; f32 fma dot (reference einsum is f32)
  const float Y0 = 0.299f,    Y1 = 0.587f,    Y2 = 0.114f;
  const float U0 = -0.14713f, U1 = -0.28886f, U2 = 0.436f;
  const float V0 = 0.615f,    V1 = -0.51499f, V2 = -0.10001f;

  float aWp = 0.f, aWn = 0.f;   // + image / - image integer parts (f32-exact)
  float aEp = 0.f, aEn = 0.f;   // soft parts

  const int pair = blockIdx.x * BLOCK + threadIdx.x;   // 2 adjacent pixels
  const int p    = pair << 1;
  const int b    = p >> 16;              // batch (uniform per block: 512 | HW)
  const int hw   = p & (HW - 1);
  const float2* pi = (const float2*)(img_in  + (size_t)b * (3 * HW) + hw);
  const float2* pr = (const float2*)(img_ref + (size_t)b * (3 * HW) + hw);
  float2 r0 = pi[0], g0 = pi[HW / 2], b0 = pi[HW];     // strides in float2 units
  float2 r1 = pr[0], g1 = pr[HW / 2], b1 = pr[HW];

  const float rr0[2] = { r0.x, r0.y }, gg0[2] = { g0.x, g0.y }, bb0[2] = { b0.x, b0.y };
  const float rr1[2] = { r1.x, r1.y }, gg1[2] = { g1.x, g1.y }, bb1[2] = { b1.x, b1.y };

  #pragma unroll
  for (int i = 0; i < PXT; ++i) {
    float ri = rr0[i], gi = gg0[i], bi = bb0[i];
    float rj = rr1[i], gj = gg1[i], bj = bb1[i];

    // RGB
    contrib(ri, ivs, go, Ls, aWp, aEp);
    contrib(gi, ivs, go, Ls, aWp, aEp);
    contrib(bi, ivs, go, Ls, aWp, aEp);
    contrib(rj, ivs, go, Ls, aWn, aEn);
    contrib(gj, ivs, go, Ls, aWn, aEn);
    contrib(bj, ivs, go, Ls, aWn, aEn);

    // YUV in f32 (j-ascending fma chain like the einsum)
    float yi = fmaf(Y2, bi, fmaf(Y1, gi, Y0 * ri));
    float ui = fmaf(U2, bi, fmaf(U1, gi, U0 * ri));
    float vi = fmaf(V2, bi, fmaf(V1, gi, V0 * ri));
    float yj = fmaf(Y2, bj, fmaf(Y1, gj, Y0 * rj));
    float uj = fmaf(U2, bj, fmaf(U1, gj, U0 * rj));
    float vj = fmaf(V2, bj, fmaf(V1, gj, V0 * rj));

    contrib(yi, ivs, go, Ls, aWp, aEp);
    contrib(ui, ivs, go, Ls, aWp, aEp);
    contrib(vi, ivs, go, Ls, aWp, aEp);
    contrib(yj, ivs, go, Ls, aWn, aEn);
    contrib(uj, ivs, go, Ls, aWn, aEn);
    contrib(vj, ivs, go, Ls, aWn, aEn);
  }

  float  aW = aWp - aWn;                      // exact (integer-valued f32)
  double aE = (double)aEp - (double)aEn;

  // wave(64) shuffle reduction, then cross-wave via LDS
  #pragma unroll
  for (int off = 32; off > 0; off >>= 1) {
    aW += __shfl_down(aW, off);               // wave sum <= 98304: f32-exact
    aE += __shfl_down(aE, off);
  }
  int wv = threadIdx.x >> 6;
  if ((threadIdx.x & 63) == 0) { redW[wv] = (double)aW; redE[wv] = aE; }
  __syncthreads();

  if (threadIdx.x == 0) {
    double sW = 0.0, sE = 0.0;
    #pragma unroll
    for (int w = 0; w < 4; ++w) { sW += redW[w]; sE += redE[w]; }
    // Publish: data relaxed, tags release (agent scope crosses XCD L2s).
    __hip_atomic_store(&pW[blockIdx.x], sW, __ATOMIC_RELAXED, __HIP_MEMORY_SCOPE_AGENT);
    __hip_atomic_store(&pE[blockIdx.x], sE, __ATOMIC_RELAXED, __HIP_MEMORY_SCOPE_AGENT);
    __hip_atomic_store(&tagA[blockIdx.x], MAG1 ^ (unsigned)blockIdx.x,
                       __ATOMIC_RELEASE, __HIP_MEMORY_SCOPE_AGENT);
    __hip_atomic_store(&tagB[blockIdx.x], MAG2 ^ (unsigned)blockIdx.x,
                       __ATOMIC_RELEASE, __HIP_MEMORY_SCOPE_AGENT);
  }

  if (blockIdx.x != 0) return;   // publishers exit; no one waits on them

  // ---- block 0: spin until all slots published, then reduce (R4 order) ----
  double sW = 0.0, sE = 0.0;
  for (int s = threadIdx.x; s < NBLK; s += BLOCK) {
    while (__hip_atomic_load(&tagA[s], __ATOMIC_ACQUIRE, __HIP_MEMORY_SCOPE_AGENT)
               != (MAG1 ^ (unsigned)s) ||
           __hip_atomic_load(&tagB[s], __ATOMIC_ACQUIRE, __HIP_MEMORY_SCOPE_AGENT)
               != (MAG2 ^ (unsigned)s)) { }
    sW += __hip_atomic_load(&pW[s], __ATOMIC_RELAXED, __HIP_MEMORY_SCOPE_AGENT);
    sE += __hip_atomic_load(&pE[s], __ATOMIC_RELAXED, __HIP_MEMORY_SCOPE_AGENT);
  }
  #pragma unroll
  for (int off = 32; off > 0; off >>= 1) {
    sW += __shfl_down(sW, off);
    sE += __shfl_down(sE, off);
  }
  __syncthreads();   // redW/redE reuse after phase-1 writes
  int wv2 = threadIdx.x >> 6;
  if ((threadIdx.x & 63) == 0) { redW[wv2] = sW; redE[wv2] = sE; }
  __syncthreads();
  if (threadIdx.x == 0) {
    double tW = 0.0, tE = 0.0;
    #pragma unroll
    for (int w = 0; w < 4; ++w) { tW += redW[w]; tE += redE[w]; }
    out[0] = (float)((tW + tE) * (1.0 / (double)NPIX));
  }
}

extern "C" void kernel_launch(void* const* d_in, const int* in_sizes, int n_in,
                              void* d_out, int out_size, void* d_ws, size_t ws_size,
                              hipStream_t stream) {
  const float* img_in  = (const float*)d_in[0];
  const float* img_ref = (const float*)d_in[1];
  float* out = (float*)d_out;

  // ws layout: pW[1024] | pE[1024] doubles (16 KB), then tagA[1024], tagB[1024].
  char* ws = (char*)d_ws;
  double*   pW   = (double*)ws;
  double*   pE   = (double*)(ws + NBLK * sizeof(double));
  unsigned* tagA = (unsigned*)(ws + 2 * NBLK * sizeof(double));
  unsigned* tagB = (unsigned*)(ws + 2 * NBLK * sizeof(double) + NBLK * sizeof(unsigned));

  hl_onepass<<<NBLK, BLOCK, 0, stream>>>(img_in, img_ref, pW, pE, tagA, tagB, out);
}

// Round 4
// 66.963 us; speedup vs baseline: 1.8662x; 1.2271x over previous
//
#include <hip/hip_runtime.h>

// HistogramLoss: total = emd(hist(rgb_in),hist(rgb_ref)) + emd(hist(yuv_in),hist(yuv_ref))
// emd collapses to sum_k (64-k)*(h1_k - h2_k); bins tile [-0.05,1.05] disjointly.
//
// R4 (66.2us, absmax 0.0): all-f32 bin-coordinate formulation, two dispatches.
// R5 (125us): cooperative grid.sync ~45us in-kernel -- grid barrier is ~10x
//   the dispatch it saved. REVERTED.
// R6 (82.2us): publish/spin last-reducer: agent-scope release stores + block-0
//   acquire polling across non-coherent XCD L2s pay HBM-class round trips;
//   +16us vs R4. REVERTED. Lesson: on MI355X a 2nd dispatch is CHEAPER than
//   any in-kernel global handshake.
// R7: back to R4's two-dispatch structure, with two shavings:
//   (a) single-candidate contrib: bin-k window is |g-k|<0.5 with k=rintf(g);
//       f=g-rintf(g) is Sterbenz-exact, t=0.5-|f| is bit-identical to R4's
//       passing-candidate t in both branches (exactness proof in-session);
//       ~35% fewer VALU ops in the hot loop. aW/aE bits unchanged.
//   (b) PXT=4 via float4 loads (16B/lane), NBLK=512 -> shorter dispatch
//       drain; hl_final reads 8KB.

#define HW    65536             // 256*256
#define NPIX  524288            // 8 * HW pixel positions
#define BLOCK 256
#define PXT   4                 // pixels per thread (adjacent -> float4 loads)
#define NBLK  (NPIX / (BLOCK * PXT))   // 512

__device__ __forceinline__ void contrib(float v, float ivs, float go, float Ls,
                                        float& aW, float& aE) {
  float u = (v + 1.0f) * 0.5f;      // matches reference rounding (add then mul)
  float g = fmaf(u, ivs, go);       // (u+0.05)/step - 0.5 ; bin center k sits at g==k
  float k = rintf(g);               // single candidate: window is |g-k| < 0.5
  float f = g - k;                  // exact (Sterbenz; |g|<2^23)
  float t = 0.5f - fabsf(f);        // bit-identical to R4's passing-candidate t
  bool in = (t > 0.0f) && (fabsf(k - 31.5f) < 32.0f);  // strict t>0 ; k in [0,63]
  float w = in ? (64.0f - k) : 0.0f;
  float z = t * Ls;                 // z = ln(1.01f) * step * t'
  float e = fmaf(0.5f * z, z, z);   // expm1(z), O(z^3) ~ 1e-13 dropped
  aW += w;                          // exact integer part (f32-exact)
  aE  = fmaf(w, e, aE);
}

__global__ __launch_bounds__(BLOCK) void hl_partial(
    const float* __restrict__ img_in, const float* __restrict__ img_ref,
    double* __restrict__ partials) {
  __shared__ double redW[4], redE[4];

  // Replicate np.linspace(-0.05, 1.05, 65) step in f64, then cast constants.
  const double step = (1.05 - (-0.05)) / 64.0;
  const float  ivs = (float)(1.0 / step);            // 1/step
  const float  go  = (float)(0.05 / step - 0.5);     // (u+0.05)/step - 0.5 offset
  const float  Ls  = (float)(log((double)1.01f) * step);  // ln(f32(1.01)) * step

  // f32 YUV coefficients; f32 fma dot (reference einsum is f32)
  const float Y0 = 0.299f,    Y1 = 0.587f,    Y2 = 0.114f;
  const float U0 = -0.14713f, U1 = -0.28886f, U2 = 0.436f;
  const float V0 = 0.615f,    V1 = -0.51499f, V2 = -0.10001f;

  float aWp = 0.f, aWn = 0.f;   // + image / - image integer parts (f32-exact)
  float aEp = 0.f, aEn = 0.f;   // soft parts

  const int idx = blockIdx.x * BLOCK + threadIdx.x;    // 4 adjacent pixels
  const int p   = idx << 2;
  const int b   = p >> 16;               // batch (uniform per block: 1024 | HW)
  const int hw  = p & (HW - 1);
  const float4* pi = (const float4*)(img_in  + (size_t)b * (3 * HW) + hw);
  const float4* pr = (const float4*)(img_ref + (size_t)b * (3 * HW) + hw);
  float4 r0 = pi[0], g0 = pi[HW / 4], b0 = pi[HW / 2];  // strides in float4 units
  float4 r1 = pr[0], g1 = pr[HW / 4], b1 = pr[HW / 2];

  const float rr0[4] = { r0.x, r0.y, r0.z, r0.w };
  const float gg0[4] = { g0.x, g0.y, g0.z, g0.w };
  const float bb0[4] = { b0.x, b0.y, b0.z, b0.w };
  const float rr1[4] = { r1.x, r1.y, r1.z, r1.w };
  const float gg1[4] = { g1.x, g1.y, g1.z, g1.w };
  const float bb1[4] = { b1.x, b1.y, b1.z, b1.w };

  #pragma unroll
  for (int i = 0; i < PXT; ++i) {
    float ri = rr0[i], gi = gg0[i], bi = bb0[i];
    float rj = rr1[i], gj = gg1[i], bj = bb1[i];

    // RGB
    contrib(ri, ivs, go, Ls, aWp, aEp);
    contrib(gi, ivs, go, Ls, aWp, aEp);
    contrib(bi, ivs, go, Ls, aWp, aEp);
    contrib(rj, ivs, go, Ls, aWn, aEn);
    contrib(gj, ivs, go, Ls, aWn, aEn);
    contrib(bj, ivs, go, Ls, aWn, aEn);

    // YUV in f32 (j-ascending fma chain like the einsum)
    float yi = fmaf(Y2, bi, fmaf(Y1, gi, Y0 * ri));
    float ui = fmaf(U2, bi, fmaf(U1, gi, U0 * ri));
    float vi = fmaf(V2, bi, fmaf(V1, gi, V0 * ri));
    float yj = fmaf(Y2, bj, fmaf(Y1, gj, Y0 * rj));
    float uj = fmaf(U2, bj, fmaf(U1, gj, U0 * rj));
    float vj = fmaf(V2, bj, fmaf(V1, gj, V0 * rj));

    contrib(yi, ivs, go, Ls, aWp, aEp);
    contrib(ui, ivs, go, Ls, aWp, aEp);
    contrib(vi, ivs, go, Ls, aWp, aEp);
    contrib(yj, ivs, go, Ls, aWn, aEn);
    contrib(uj, ivs, go, Ls, aWn, aEn);
    contrib(vj, ivs, go, Ls, aWn, aEn);
  }

  float  aW = aWp - aWn;                      // exact (integer-valued f32)
  double aE = (double)aEp - (double)aEn;

  // wave(64) shuffle reduction, then cross-wave via LDS
  #pragma unroll
  for (int off = 32; off > 0; off >>= 1) {
    aW += __shfl_down(aW, off);               // wave sum <= 786432: f32-exact
    aE += __shfl_down(aE, off);
  }
  int wv = threadIdx.x >> 6;
  if ((threadIdx.x & 63) == 0) { redW[wv] = (double)aW; redE[wv] = aE; }
  __syncthreads();

  if (threadIdx.x == 0) {
    double sW = 0.0, sE = 0.0;
    #pragma unroll
    for (int w = 0; w < 4; ++w) { sW += redW[w]; sE += redE[w]; }
    partials[2 * blockIdx.x]     = sW;  // unconditional store: no ws init needed
    partials[2 * blockIdx.x + 1] = sE;
  }
}

__global__ __launch_bounds__(BLOCK) void hl_final(
    const double* __restrict__ partials, float* __restrict__ out) {
  __shared__ double redW[4], redE[4];
  double sW = 0.0, sE = 0.0;
  for (int b = threadIdx.x; b < NBLK; b += BLOCK) {   // 2 slots per thread
    sW += partials[2 * b];
    sE += partials[2 * b + 1];
  }
  #pragma unroll
  for (int off = 32; off > 0; off >>= 1) {
    sW += __shfl_down(sW, off);
    sE += __shfl_down(sE, off);
  }
  int wv = threadIdx.x >> 6;
  if ((threadIdx.x & 63) == 0) { redW[wv] = sW; redE[wv] = sE; }
  __syncthreads();
  if (threadIdx.x == 0) {
    double tW = 0.0, tE = 0.0;
    #pragma unroll
    for (int w = 0; w < 4; ++w) { tW += redW[w]; tE += redE[w]; }
    out[0] = (float)((tW + tE) * (1.0 / (double)NPIX));
  }
}

extern "C" void kernel_launch(void* const* d_in, const int* in_sizes, int n_in,
                              void* d_out, int out_size, void* d_ws, size_t ws_size,
                              hipStream_t stream) {
  const float* img_in  = (const float*)d_in[0];
  const float* img_ref = (const float*)d_in[1];
  float* out = (float*)d_out;
  double* partials = (double*)d_ws;   // 2*NBLK doubles = 8 KB

  hl_partial<<<NBLK, BLOCK, 0, stream>>>(img_in, img_ref, partials);
  hl_final<<<1, BLOCK, 0, stream>>>(partials, out);
}